// Round 3
// baseline (197.564 us; speedup 1.0000x reference)
//
#include <hip/hip_runtime.h>

typedef _Float16 f16;
typedef _Float16 f16x8 __attribute__((ext_vector_type(8)));
typedef float f32x4 __attribute__((ext_vector_type(4)));

#define BK 32

// Async global->LDS, 16B per lane: lane i's 16B lands at base + i*16.
__device__ __forceinline__ void g2l16(const void* g, void* l) {
    __builtin_amdgcn_global_load_lds(
        (const __attribute__((address_space(1))) void*)g,
        (__attribute__((address_space(3))) void*)l, 16, 0, 0);
}

// Counted vmcnt wait (literal required in asm string).
template <int N> __device__ __forceinline__ void wait_vmcnt();
template <> __device__ __forceinline__ void wait_vmcnt<0>() { asm volatile("s_waitcnt vmcnt(0)" ::: "memory"); }
template <> __device__ __forceinline__ void wait_vmcnt<4>() { asm volatile("s_waitcnt vmcnt(4)" ::: "memory"); }

__device__ __forceinline__ float soft1(float a, float thr, float w, float s) {
    return copysignf(fmaxf(a - thr, 0.0f), w) * s;
}

__device__ __forceinline__ float thr4(float a0, float a1, float a2, float a3) {
    float lo01 = fminf(a0, a1), hi01 = fmaxf(a0, a1);
    float lo23 = fminf(a2, a3), hi23 = fmaxf(a2, a3);
    return fminf(fmaxf(lo01, lo23), fminf(hi01, hi23));
}

// Weights-only prep (x cast is folded into GEMM1's fp32 staging):
//   [0, nSpInB)  -> sparsify w_in   (2:4 along R), out winT  [R][D]
//   [.., +nSpOutB)-> sparsify w_out^T (2:4 along D), out woutT [D][R]
__global__ __launch_bounds__(256) void prep_kernel(
    const float* __restrict__ Wi, f16* __restrict__ winT, const float* __restrict__ sci,
    const float* __restrict__ Wo, f16* __restrict__ woutT, const float* __restrict__ sco,
    int D, int R, int nSpInB)
{
    int b = blockIdx.x;
    int tid = threadIdx.x;
    if (b < nSpInB) {
        int t = b * 256 + tid;              // t = rg*D + d (coalesced writes)
        int RG = R >> 2;
        if (t >= RG * D) return;
        int rg = t / D, d = t - rg * D;
        float s = *sci;
        float4 w = *reinterpret_cast<const float4*>(Wi + (size_t)d * R + rg * 4);
        float a0 = fabsf(w.x), a1 = fabsf(w.y), a2 = fabsf(w.z), a3 = fabsf(w.w);
        float thr = thr4(a0, a1, a2, a3);
        size_t base = (size_t)(rg * 4) * D + d;
        winT[base]                 = (f16)soft1(a0, thr, w.x, s);
        winT[base + D]             = (f16)soft1(a1, thr, w.y, s);
        winT[base + 2 * (size_t)D] = (f16)soft1(a2, thr, w.z, s);
        winT[base + 3 * (size_t)D] = (f16)soft1(a3, thr, w.w, s);
    } else {
        int t = (b - nSpInB) * 256 + tid;   // t = dg*R + r
        if (t >= (D >> 2) * R) return;
        int dg = t / R, r = t - dg * R;
        float s = *sco;
        size_t i0 = (size_t)(dg * 4) * R + r;
        float w0 = Wo[i0], w1 = Wo[i0 + R], w2 = Wo[i0 + 2 * (size_t)R], w3 = Wo[i0 + 3 * (size_t)R];
        float a0 = fabsf(w0), a1 = fabsf(w1), a2 = fabsf(w2), a3 = fabsf(w3);
        float thr = thr4(a0, a1, a2, a3);
        woutT[i0]                 = (f16)soft1(a0, thr, w0, s);
        woutT[i0 + R]             = (f16)soft1(a1, thr, w1, s);
        woutT[i0 + 2 * (size_t)R] = (f16)soft1(a2, thr, w2, s);
        woutT[i0 + 3 * (size_t)R] = (f16)soft1(a3, thr, w3, s);
    }
}

// C[M][N] = A[M][K] @ Bt[N][K]^T, fp32 accum. A is f16 OR fp32 (AT param);
// fp32 A is staged raw to LDS and converted f32->f16 (RTN, same as the old
// prep cast) at fragment-load time.
// fp32-A LDS tile has 128B row stride -> would be a 16-way bank conflict;
// fix per rule 21: LINEAR g2l16 dest + XOR-swizzled GLOBAL source
// (chunk ^= row&7) + the same XOR on the read address.
// Depth-2 counted-vmcnt pipeline (T4), raw s_barrier; XCD-bijective swizzle.
template <int TBM, int TBN, typename AT, typename OT, bool BIAS>
__global__ __launch_bounds__(256) void gemm_bt(
    const AT* __restrict__ A, const f16* __restrict__ Bt, OT* __restrict__ C,
    const float* __restrict__ bias, int M, int N, int K)
{
    constexpr bool AF32 = sizeof(AT) == 4;
    constexpr int MI = TBM / 32;   // A-fragments per wave
    constexpr int NF = TBN / 32;   // B-fragments per wave
    constexpr int HM = TBM / 2;    // per-wave M span
    constexpr int HN = TBN / 2;    // per-wave N span
    constexpr int LA = TBM * BK * (int)sizeof(AT) / 4096;  // A g2l16 per thread/tile
    constexpr int LB = TBN * BK * 2 / 4096;                // B g2l16 per thread/tile
    constexpr int L  = LA + LB;
    static_assert(L == 4, "wait_vmcnt<L> instantiations assume L==4");
    __shared__ AT  As[2][TBM * BK];
    __shared__ f16 Bs[2][TBN * BK];

    const int tid  = threadIdx.x;
    const int lane = tid & 63;
    const int w    = tid >> 6;
    const int wm   = w & 1;
    const int wn   = w >> 1;
    const int l16  = lane & 15;
    const int quad = lane >> 4;

    // XCD swizzle: HW round-robins consecutive dispatches across 8 XCDs.
    const int nbx = N / TBN;
    const int nb  = gridDim.x;
    int d = blockIdx.x;
    int wgid = ((nb & 7) == 0) ? ((d & 7) * (nb >> 3) + (d >> 3)) : d;
    int by = wgid / nbx;
    int bx = wgid - by * nbx;
    const int bm = by * TBM;
    const int bn = bx * TBN;

    // B staging (f16): one wave-g2l16 covers 16 rows x 32 halves.
    const int srow = lane >> 2;
    const int scol = (lane & 3) * 8;
    const f16* gB = Bt + (size_t)(bn + w * (TBN / 4) + srow) * K + scol;

    // A staging: f16 path mirrors B; fp32 path covers 8 rows x 32 floats per
    // g2l16 with the source chunk XOR-swizzled so the linear LDS write gives
    // a bank-friendly swizzled layout.
    const int srowA = AF32 ? (lane >> 3) : srow;
    const int scolA = AF32 ? (((lane & 7) ^ (lane >> 3)) * 4) : scol;
    const AT* gA = A + (size_t)(bm + w * (TBM / 4) + srowA) * K + scolA;

    f32x4 acc[MI][NF] = {};

    auto STAGE = [&](int buf, int t) {
        const int k0 = t * BK;
        AT*  lA = &As[buf][(w * (TBM / 4)) * BK];
        f16* lB = &Bs[buf][(w * (TBN / 4)) * BK];
        if constexpr (AF32) {
#pragma unroll
            for (int i = 0; i < (TBM / 4) / 8; ++i)
                g2l16(gA + k0 + i * 8 * (size_t)K, lA + i * 8 * BK);
        } else {
#pragma unroll
            for (int i = 0; i < (TBM / 4) / 16; ++i)
                g2l16(gA + k0 + i * 16 * (size_t)K, lA + i * 16 * BK);
        }
#pragma unroll
        for (int i = 0; i < (TBN / 4) / 16; ++i)
            g2l16(gB + k0 + i * 16 * (size_t)K, lB + i * 16 * BK);
    };

    auto LOADFRAG = [&](int buf, f16x8* af, f16x8* bf) {
        if constexpr (AF32) {
#pragma unroll
            for (int m = 0; m < MI; ++m) {
                int lr = wm * HM + m * 16 + l16;
                const char* row = reinterpret_cast<const char*>(&As[buf][lr * BK]);
                int swz = (lr & 7) << 4;
                f32x4 lo = *reinterpret_cast<const f32x4*>(row + (((quad * 32)      ) ^ swz));
                f32x4 hi = *reinterpret_cast<const f32x4*>(row + (((quad * 32) + 16 ) ^ swz));
                f16x8 a;
#pragma unroll
                for (int j = 0; j < 4; ++j) { a[j] = (f16)lo[j]; a[j + 4] = (f16)hi[j]; }
                af[m] = a;
            }
        } else {
#pragma unroll
            for (int m = 0; m < MI; ++m)
                af[m] = *reinterpret_cast<const f16x8*>(
                    &As[buf][(wm * HM + m * 16 + l16) * BK + quad * 8]);
        }
#pragma unroll
        for (int n = 0; n < NF; ++n)
            bf[n] = *reinterpret_cast<const f16x8*>(
                &Bs[buf][(wn * HN + n * 16 + l16) * BK + quad * 8]);
    };

    auto MFMA_ALL = [&](f16x8* af, f16x8* bf) {
#pragma unroll
        for (int m = 0; m < MI; ++m)
#pragma unroll
            for (int n = 0; n < NF; ++n)
                acc[m][n] = __builtin_amdgcn_mfma_f32_16x16x32_f16(af[m], bf[n], acc[m][n], 0, 0, 0);
    };

    const int nk = K / BK;   // 64 for GEMM1, 16 for GEMM2 (>= 4, even)
    STAGE(0, 0);
    STAGE(1, 1);
    for (int t = 0; t < nk - 2; ++t) {
        wait_vmcnt<4>();                       // tile t landed; t+1 in flight
        __builtin_amdgcn_s_barrier();
        __builtin_amdgcn_sched_barrier(0);
        f16x8 af[MI], bf[NF];
        LOADFRAG(t & 1, af, bf);
        asm volatile("s_waitcnt lgkmcnt(0)" ::: "memory");
        __builtin_amdgcn_sched_barrier(0);     // rule 18
        __builtin_amdgcn_s_barrier();          // buf (t&1) released by all waves
        STAGE(t & 1, t + 2);                   // async overwrite; overlaps MFMA
        MFMA_ALL(af, bf);
    }
    {   // t = nk-2: tiles nk-2, nk-1 in flight, nothing left to stage
        wait_vmcnt<4>();
        __builtin_amdgcn_s_barrier();
        __builtin_amdgcn_sched_barrier(0);
        f16x8 af[MI], bf[NF];
        LOADFRAG(nk & 1, af, bf);              // (nk-2)&1
        MFMA_ALL(af, bf);
    }
    {   // t = nk-1: drain fully
        wait_vmcnt<0>();
        __builtin_amdgcn_s_barrier();
        __builtin_amdgcn_sched_barrier(0);
        f16x8 af[MI], bf[NF];
        LOADFRAG((nk - 1) & 1, af, bf);
        MFMA_ALL(af, bf);
    }

    // epilogue: C/D layout row = quad*4 + r, col = lane&15
#pragma unroll
    for (int m = 0; m < MI; ++m) {
        int row_base = bm + wm * HM + m * 16 + quad * 4;
#pragma unroll
        for (int n = 0; n < NF; ++n) {
            int col = bn + wn * HN + n * 16 + l16;
            float b = BIAS ? bias[col] : 0.0f;
#pragma unroll
            for (int r = 0; r < 4; ++r) {
                float v = acc[m][n][r];
                size_t idx = (size_t)(row_base + r) * N + col;
                if constexpr (BIAS) C[idx] = (OT)(v + b);
                else                C[idx] = (OT)v;
            }
        }
    }
}

extern "C" void kernel_launch(void* const* d_in, const int* in_sizes, int n_in,
                              void* d_out, int out_size, void* d_ws, size_t ws_size,
                              hipStream_t stream)
{
    const float* x      = (const float*)d_in[0];
    const float* w_in   = (const float*)d_in[1];
    const float* w_out  = (const float*)d_in[2];
    const float* bias   = (const float*)d_in[3];
    const float* sc_in  = (const float*)d_in[4];
    const float* sc_out = (const float*)d_in[5];

    const int D = in_sizes[3];            // 2048
    const int R = in_sizes[1] / D;        // 512
    const int M = in_sizes[0] / D;        // 8192 (B*S)

    f16* winT  = (f16*)d_ws;                      // [R][D]
    f16* woutT = winT + (size_t)R * D;            // [D][R]
    f16* h     = woutT + (size_t)D * R;           // [M][R]
    float* out = (float*)d_out;

    const int nSpInB  = ((R / 4) * D + 255) / 256;
    const int nSpOutB = ((D / 4) * R + 255) / 256;
    prep_kernel<<<nSpInB + nSpOutB, 256, 0, stream>>>(
        w_in, winT, sc_in, w_out, woutT, sc_out, D, R, nSpInB);

    // GEMM1: M=8192, N=512, K=2048. A = raw x (fp32), cast fused into
    // staging. 64x128 tile, 512 blocks = 2/CU.
    gemm_bt<64, 128, float, f16, false><<<(R / 128) * (M / 64), 256, 0, stream>>>(
        x, winT, h, nullptr, M, R, D);
    // GEMM2: M=8192, N=2048, K=512. 128x128 tile, 1024 blocks = 4/CU.
    gemm_bt<128, 128, f16, float, true><<<(D / 128) * (M / 128), 256, 0, stream>>>(
        h, woutT, out, bias, M, D, R);
}

// Round 4
// 193.214 us; speedup vs baseline: 1.0225x; 1.0225x over previous
//
#include <hip/hip_runtime.h>

typedef _Float16 f16;
typedef _Float16 f16x8 __attribute__((ext_vector_type(8)));
typedef float f32x4 __attribute__((ext_vector_type(4)));

#define BK 32

// Async global->LDS, 16B per lane: lane i's 16B lands at base + i*16.
__device__ __forceinline__ void g2l16(const void* g, void* l) {
    __builtin_amdgcn_global_load_lds(
        (const __attribute__((address_space(1))) void*)g,
        (__attribute__((address_space(3))) void*)l, 16, 0, 0);
}

// Counted vmcnt wait (literal required in asm string).
template <int N> __device__ __forceinline__ void wait_vmcnt();
template <> __device__ __forceinline__ void wait_vmcnt<0>() { asm volatile("s_waitcnt vmcnt(0)" ::: "memory"); }
template <> __device__ __forceinline__ void wait_vmcnt<4>() { asm volatile("s_waitcnt vmcnt(4)" ::: "memory"); }

__device__ __forceinline__ float soft1(float a, float thr, float w, float s) {
    return copysignf(fmaxf(a - thr, 0.0f), w) * s;
}

__device__ __forceinline__ float thr4(float a0, float a1, float a2, float a3) {
    float lo01 = fminf(a0, a1), hi01 = fmaxf(a0, a1);
    float lo23 = fminf(a2, a3), hi23 = fmaxf(a2, a3);
    return fminf(fmaxf(lo01, lo23), fminf(hi01, hi23));
}

// Weights-only prep (x cast is folded into GEMM1's reg-staged A path):
//   [0, nSpInB)   -> sparsify w_in   (2:4 along R), out winT  [R][D]
//   [.., +nSpOutB)-> sparsify w_out^T (2:4 along D), out woutT [D][R]
__global__ __launch_bounds__(256) void prep_kernel(
    const float* __restrict__ Wi, f16* __restrict__ winT, const float* __restrict__ sci,
    const float* __restrict__ Wo, f16* __restrict__ woutT, const float* __restrict__ sco,
    int D, int R, int nSpInB)
{
    int b = blockIdx.x;
    int tid = threadIdx.x;
    if (b < nSpInB) {
        int t = b * 256 + tid;              // t = rg*D + d (coalesced writes)
        int RG = R >> 2;
        if (t >= RG * D) return;
        int rg = t / D, d = t - rg * D;
        float s = *sci;
        float4 w = *reinterpret_cast<const float4*>(Wi + (size_t)d * R + rg * 4);
        float a0 = fabsf(w.x), a1 = fabsf(w.y), a2 = fabsf(w.z), a3 = fabsf(w.w);
        float thr = thr4(a0, a1, a2, a3);
        size_t base = (size_t)(rg * 4) * D + d;
        winT[base]                 = (f16)soft1(a0, thr, w.x, s);
        winT[base + D]             = (f16)soft1(a1, thr, w.y, s);
        winT[base + 2 * (size_t)D] = (f16)soft1(a2, thr, w.z, s);
        winT[base + 3 * (size_t)D] = (f16)soft1(a3, thr, w.w, s);
    } else {
        int t = (b - nSpInB) * 256 + tid;   // t = dg*R + r
        if (t >= (D >> 2) * R) return;
        int dg = t / R, r = t - dg * R;
        float s = *sco;
        size_t i0 = (size_t)(dg * 4) * R + r;
        float w0 = Wo[i0], w1 = Wo[i0 + R], w2 = Wo[i0 + 2 * (size_t)R], w3 = Wo[i0 + 3 * (size_t)R];
        float a0 = fabsf(w0), a1 = fabsf(w1), a2 = fabsf(w2), a3 = fabsf(w3);
        float thr = thr4(a0, a1, a2, a3);
        woutT[i0]                 = (f16)soft1(a0, thr, w0, s);
        woutT[i0 + R]             = (f16)soft1(a1, thr, w1, s);
        woutT[i0 + 2 * (size_t)R] = (f16)soft1(a2, thr, w2, s);
        woutT[i0 + 3 * (size_t)R] = (f16)soft1(a3, thr, w3, s);
    }
}

// C[M][N] = A[M][K] @ Bt[N][K]^T, fp32 accum. LDS tiles are ALWAYS f16
// (round-2 proven layout + fragment-read path). Two A staging modes:
//   AT = f16  : g2l16 direct (round-2 identical).
//   AT = float: reg-staged with fused cast — global_load f32x4 issued one
//               iteration early (overlaps MFMA), cvt+ds_write_b128 at the
//               top of the iteration producing the SAME LDS image g2l16
//               would. Cast stays OFF the fragment-read critical path
//               (round-3 lesson).
// Depth-2 counted-vmcnt pipeline (T4), raw s_barrier, 2 barriers/K-step;
// XCD-bijective block swizzle.
template <int TBM, int TBN, typename AT, typename OT, bool BIAS>
__global__ __launch_bounds__(256) void gemm_bt(
    const AT* __restrict__ A, const f16* __restrict__ Bt, OT* __restrict__ C,
    const float* __restrict__ bias, int M, int N, int K)
{
    constexpr bool AF32 = sizeof(AT) == 4;
    constexpr int MI = TBM / 32;   // A-fragments per wave
    constexpr int NF = TBN / 32;   // B-fragments per wave
    constexpr int HM = TBM / 2;    // per-wave M span
    constexpr int HN = TBN / 2;    // per-wave N span
    __shared__ f16 As[2][TBM * BK];
    __shared__ f16 Bs[2][TBN * BK];

    const int tid  = threadIdx.x;
    const int lane = tid & 63;
    const int w    = tid >> 6;
    const int wm   = w & 1;
    const int wn   = w >> 1;
    const int l16  = lane & 15;
    const int quad = lane >> 4;

    // XCD swizzle: HW round-robins consecutive dispatches across 8 XCDs.
    const int nbx = N / TBN;
    const int nb  = gridDim.x;
    int d = blockIdx.x;
    int wgid = ((nb & 7) == 0) ? ((d & 7) * (nb >> 3) + (d >> 3)) : d;
    int by = wgid / nbx;
    int bx = wgid - by * nbx;
    const int bm = by * TBM;
    const int bn = bx * TBN;

    // Staging geometry (per 16B chunk): row = lane>>2, col = (lane&3)*8.
    const int srow = lane >> 2;
    const int scol = (lane & 3) * 8;
    const f16* gB = Bt + (size_t)(bn + w * (TBN / 4) + srow) * K + scol;
    const AT*  gA = A  + (size_t)(bm + w * (TBM / 4) + srow) * K + scol;
    const int  aoff = (w * (TBM / 4) + srow) * BK + scol;   // LDS f16 offset

    f32x4 acc[MI][NF] = {};

    auto STAGE_B = [&](int buf, int t) {
        f16* lB = &Bs[buf][(w * (TBN / 4)) * BK];
#pragma unroll
        for (int i = 0; i < (TBN / 4) / 16; ++i)
            g2l16(gB + (size_t)t * BK + i * 16 * (size_t)K, lB + i * 16 * BK);
    };

    auto LOADFRAG = [&](int buf, f16x8* af, f16x8* bf) {
#pragma unroll
        for (int m = 0; m < MI; ++m)
            af[m] = *reinterpret_cast<const f16x8*>(
                &As[buf][(wm * HM + m * 16 + l16) * BK + quad * 8]);
#pragma unroll
        for (int n = 0; n < NF; ++n)
            bf[n] = *reinterpret_cast<const f16x8*>(
                &Bs[buf][(wn * HN + n * 16 + l16) * BK + quad * 8]);
    };

    auto MFMA_ALL = [&](f16x8* af, f16x8* bf) {
#pragma unroll
        for (int m = 0; m < MI; ++m)
#pragma unroll
            for (int n = 0; n < NF; ++n)
                acc[m][n] = __builtin_amdgcn_mfma_f32_16x16x32_f16(af[m], bf[n], acc[m][n], 0, 0, 0);
    };

    const int nk = K / BK;   // 64 for GEMM1, 16 for GEMM2 (even, >= 4)

    if constexpr (AF32) {
        auto ALOAD = [&](int t, f32x4& r0, f32x4& r1) {
            const float* p = (const float*)gA + (size_t)t * BK;
            r0 = *reinterpret_cast<const f32x4*>(p);
            r1 = *reinterpret_cast<const f32x4*>(p + 4);
        };
        auto AWRITE = [&](int buf, const f32x4& r0, const f32x4& r1) {
            f16x8 v;
#pragma unroll
            for (int j = 0; j < 4; ++j) { v[j] = (f16)r0[j]; v[j + 4] = (f16)r1[j]; }
            *reinterpret_cast<f16x8*>(&As[buf][aoff]) = v;
        };
        f32x4 a0E, a1E, a0O, a1O;
        ALOAD(0, a0E, a1E); STAGE_B(0, 0);
        __builtin_amdgcn_sched_barrier(0);
        ALOAD(1, a0O, a1O); STAGE_B(1, 1);
        __builtin_amdgcn_sched_barrier(0);
        for (int t = 0; t < nk - 2; t += 2) {
            // ---- tile t (buf 0, regs E); stages tile t+2
            wait_vmcnt<4>();                    // A-regs(t)+B-lds(t) done; t+1 in flight
            __builtin_amdgcn_sched_barrier(0);
            AWRITE(0, a0E, a1E);
            asm volatile("s_waitcnt lgkmcnt(0)" ::: "memory");
            __builtin_amdgcn_sched_barrier(0);
            __builtin_amdgcn_s_barrier();       // tile t fully in LDS, all waves
            f16x8 af[MI], bf[NF];
            LOADFRAG(0, af, bf);
            asm volatile("s_waitcnt lgkmcnt(0)" ::: "memory");
            __builtin_amdgcn_sched_barrier(0);  // rule 18
            __builtin_amdgcn_s_barrier();       // buf0 released by all waves
            ALOAD(t + 2, a0E, a1E); STAGE_B(0, t + 2);
            __builtin_amdgcn_sched_barrier(0);  // pin prefetch issue before MFMA
            MFMA_ALL(af, bf);
            // ---- tile t+1 (buf 1, regs O); stages tile t+3
            wait_vmcnt<4>();
            __builtin_amdgcn_sched_barrier(0);
            AWRITE(1, a0O, a1O);
            asm volatile("s_waitcnt lgkmcnt(0)" ::: "memory");
            __builtin_amdgcn_sched_barrier(0);
            __builtin_amdgcn_s_barrier();
            LOADFRAG(1, af, bf);
            asm volatile("s_waitcnt lgkmcnt(0)" ::: "memory");
            __builtin_amdgcn_sched_barrier(0);
            __builtin_amdgcn_s_barrier();
            ALOAD(t + 3, a0O, a1O); STAGE_B(1, t + 3);
            __builtin_amdgcn_sched_barrier(0);
            MFMA_ALL(af, bf);
        }
        {   // tail: tile nk-2 (buf 0, E) — nothing left to stage
            wait_vmcnt<4>();
            __builtin_amdgcn_sched_barrier(0);
            AWRITE(0, a0E, a1E);
            asm volatile("s_waitcnt lgkmcnt(0)" ::: "memory");
            __builtin_amdgcn_sched_barrier(0);
            __builtin_amdgcn_s_barrier();
            f16x8 af[MI], bf[NF];
            LOADFRAG(0, af, bf);
            asm volatile("s_waitcnt lgkmcnt(0)" ::: "memory");
            __builtin_amdgcn_sched_barrier(0);
            MFMA_ALL(af, bf);
        }
        {   // tail: tile nk-1 (buf 1, O)
            wait_vmcnt<0>();
            __builtin_amdgcn_sched_barrier(0);
            AWRITE(1, a0O, a1O);
            asm volatile("s_waitcnt lgkmcnt(0)" ::: "memory");
            __builtin_amdgcn_sched_barrier(0);
            __builtin_amdgcn_s_barrier();
            f16x8 af[MI], bf[NF];
            LOADFRAG(1, af, bf);
            asm volatile("s_waitcnt lgkmcnt(0)" ::: "memory");
            __builtin_amdgcn_sched_barrier(0);
            MFMA_ALL(af, bf);
        }
    } else {
        auto STAGE = [&](int buf, int t) {
            f16* lA = &As[buf][(w * (TBM / 4)) * BK];
#pragma unroll
            for (int i = 0; i < (TBM / 4) / 16; ++i)
                g2l16((const f16*)gA + (size_t)t * BK + i * 16 * (size_t)K, lA + i * 16 * BK);
            STAGE_B(buf, t);
        };
        STAGE(0, 0);
        STAGE(1, 1);
        for (int t = 0; t < nk - 2; ++t) {
            wait_vmcnt<4>();                    // tile t landed; t+1 in flight
            __builtin_amdgcn_s_barrier();
            __builtin_amdgcn_sched_barrier(0);
            f16x8 af[MI], bf[NF];
            LOADFRAG(t & 1, af, bf);
            asm volatile("s_waitcnt lgkmcnt(0)" ::: "memory");
            __builtin_amdgcn_sched_barrier(0);  // rule 18
            __builtin_amdgcn_s_barrier();       // buf (t&1) released by all waves
            STAGE(t & 1, t + 2);                // async overwrite; overlaps MFMA
            MFMA_ALL(af, bf);
        }
        {   // t = nk-2
            wait_vmcnt<4>();
            __builtin_amdgcn_s_barrier();
            __builtin_amdgcn_sched_barrier(0);
            f16x8 af[MI], bf[NF];
            LOADFRAG(nk & 1, af, bf);           // (nk-2)&1
            asm volatile("s_waitcnt lgkmcnt(0)" ::: "memory");
            __builtin_amdgcn_sched_barrier(0);
            MFMA_ALL(af, bf);
        }
        {   // t = nk-1
            wait_vmcnt<0>();
            __builtin_amdgcn_s_barrier();
            __builtin_amdgcn_sched_barrier(0);
            f16x8 af[MI], bf[NF];
            LOADFRAG((nk - 1) & 1, af, bf);
            asm volatile("s_waitcnt lgkmcnt(0)" ::: "memory");
            __builtin_amdgcn_sched_barrier(0);
            MFMA_ALL(af, bf);
        }
    }

    // epilogue: C/D layout row = quad*4 + r, col = lane&15
#pragma unroll
    for (int m = 0; m < MI; ++m) {
        int row_base = bm + wm * HM + m * 16 + quad * 4;
#pragma unroll
        for (int n = 0; n < NF; ++n) {
            int col = bn + wn * HN + n * 16 + l16;
            float b = BIAS ? bias[col] : 0.0f;
#pragma unroll
            for (int r = 0; r < 4; ++r) {
                float v = acc[m][n][r];
                size_t idx = (size_t)(row_base + r) * N + col;
                if constexpr (BIAS) C[idx] = (OT)(v + b);
                else                C[idx] = (OT)v;
            }
        }
    }
}

extern "C" void kernel_launch(void* const* d_in, const int* in_sizes, int n_in,
                              void* d_out, int out_size, void* d_ws, size_t ws_size,
                              hipStream_t stream)
{
    const float* x      = (const float*)d_in[0];
    const float* w_in   = (const float*)d_in[1];
    const float* w_out  = (const float*)d_in[2];
    const float* bias   = (const float*)d_in[3];
    const float* sc_in  = (const float*)d_in[4];
    const float* sc_out = (const float*)d_in[5];

    const int D = in_sizes[3];            // 2048
    const int R = in_sizes[1] / D;        // 512
    const int M = in_sizes[0] / D;        // 8192 (B*S)

    f16* winT  = (f16*)d_ws;                      // [R][D]
    f16* woutT = winT + (size_t)R * D;            // [D][R]
    f16* h     = woutT + (size_t)D * R;           // [M][R]
    float* out = (float*)d_out;

    const int nSpInB  = ((R / 4) * D + 255) / 256;
    const int nSpOutB = ((D / 4) * R + 255) / 256;
    prep_kernel<<<nSpInB + nSpOutB, 256, 0, stream>>>(
        w_in, winT, sc_in, w_out, woutT, sc_out, D, R, nSpInB);

    // GEMM1: M=8192, N=512, K=2048. A = raw x (fp32), cast fused into the
    // reg-staged A path (overlappable). 64x128 tile, 512 blocks = 2/CU.
    gemm_bt<64, 128, float, f16, false><<<(R / 128) * (M / 64), 256, 0, stream>>>(
        x, winT, h, nullptr, M, R, D);
    // GEMM2: M=8192, N=2048, K=512. 128x128 tile, g2l16 both operands
    // (round-2 proven config), 1024 blocks = 4/CU.
    gemm_bt<128, 128, f16, float, true><<<(D / 128) * (M / 128), 256, 0, stream>>>(
        h, woutT, out, bias, M, D, R);
}

// Round 6
// 179.793 us; speedup vs baseline: 1.0988x; 1.0747x over previous
//
#include <hip/hip_runtime.h>

typedef _Float16 f16;
typedef _Float16 f16x8 __attribute__((ext_vector_type(8)));
typedef float f32x4 __attribute__((ext_vector_type(4)));

#define BK 32

// Async global->LDS, 16B per lane: lane i's 16B lands at base + i*16.
__device__ __forceinline__ void g2l16(const void* g, void* l) {
    __builtin_amdgcn_global_load_lds(
        (const __attribute__((address_space(1))) void*)g,
        (__attribute__((address_space(3))) void*)l, 16, 0, 0);
}

// Counted vmcnt wait (literal required in asm string).
template <int N> __device__ __forceinline__ void wait_vmcnt();
template <> __device__ __forceinline__ void wait_vmcnt<0>() { asm volatile("s_waitcnt vmcnt(0)" ::: "memory"); }
template <> __device__ __forceinline__ void wait_vmcnt<3>() { asm volatile("s_waitcnt vmcnt(3)" ::: "memory"); }
template <> __device__ __forceinline__ void wait_vmcnt<4>() { asm volatile("s_waitcnt vmcnt(4)" ::: "memory"); }

__device__ __forceinline__ float soft1(float a, float thr, float w, float s) {
    return copysignf(fmaxf(a - thr, 0.0f), w) * s;
}

__device__ __forceinline__ float thr4(float a0, float a1, float a2, float a3) {
    float lo01 = fminf(a0, a1), hi01 = fmaxf(a0, a1);
    float lo23 = fminf(a2, a3), hi23 = fmaxf(a2, a3);
    return fminf(fmaxf(lo01, lo23), fminf(hi01, hi23));
}

// One launch: [0, nCastB)        -> cast x fp32 -> f16 (cheaper than any
//             in-GEMM fusion: rounds 3/4 measured +32us for fused variants)
//             [nCastB, +nSpInB)  -> sparsify w_in   (2:4 along R), out winT  [R][D]
//             [.., +nSpOutB)     -> sparsify w_out^T (2:4 along D), out woutT [D][R]
__global__ __launch_bounds__(256) void prep_kernel(
    const float* __restrict__ x, f16* __restrict__ xh, int n8,
    const float* __restrict__ Wi, f16* __restrict__ winT, const float* __restrict__ sci,
    const float* __restrict__ Wo, f16* __restrict__ woutT, const float* __restrict__ sco,
    int D, int R, int nCastB, int nSpInB)
{
    int b = blockIdx.x;
    int tid = threadIdx.x;
    if (b < nCastB) {
        int i = b * 256 + tid;
        if (i < n8) {
            float4 a = reinterpret_cast<const float4*>(x)[2 * i];
            float4 c = reinterpret_cast<const float4*>(x)[2 * i + 1];
            f16x8 o = {(f16)a.x, (f16)a.y, (f16)a.z, (f16)a.w,
                       (f16)c.x, (f16)c.y, (f16)c.z, (f16)c.w};
            reinterpret_cast<f16x8*>(xh)[i] = o;
        }
    } else if (b < nCastB + nSpInB) {
        int t = (b - nCastB) * 256 + tid;   // t = rg*D + d (coalesced writes)
        int RG = R >> 2;
        if (t >= RG * D) return;
        int rg = t / D, d = t - rg * D;
        float s = *sci;
        float4 w = *reinterpret_cast<const float4*>(Wi + (size_t)d * R + rg * 4);
        float a0 = fabsf(w.x), a1 = fabsf(w.y), a2 = fabsf(w.z), a3 = fabsf(w.w);
        float thr = thr4(a0, a1, a2, a3);
        size_t base = (size_t)(rg * 4) * D + d;
        winT[base]                 = (f16)soft1(a0, thr, w.x, s);
        winT[base + D]             = (f16)soft1(a1, thr, w.y, s);
        winT[base + 2 * (size_t)D] = (f16)soft1(a2, thr, w.z, s);
        winT[base + 3 * (size_t)D] = (f16)soft1(a3, thr, w.w, s);
    } else {
        int t = (b - nCastB - nSpInB) * 256 + tid;  // t = dg*R + r
        if (t >= (D >> 2) * R) return;
        int dg = t / R, r = t - dg * R;
        float s = *sco;
        size_t i0 = (size_t)(dg * 4) * R + r;
        float w0 = Wo[i0], w1 = Wo[i0 + R], w2 = Wo[i0 + 2 * (size_t)R], w3 = Wo[i0 + 3 * (size_t)R];
        float a0 = fabsf(w0), a1 = fabsf(w1), a2 = fabsf(w2), a3 = fabsf(w3);
        float thr = thr4(a0, a1, a2, a3);
        woutT[i0]                 = (f16)soft1(a0, thr, w0, s);
        woutT[i0 + R]             = (f16)soft1(a1, thr, w1, s);
        woutT[i0 + 2 * (size_t)R] = (f16)soft1(a2, thr, w2, s);
        woutT[i0 + 3 * (size_t)R] = (f16)soft1(a3, thr, w3, s);
    }
}

// C[M][N] = A[M][K] f16 @ Bt[N][K]^T f16, fp32 accum.
// Round-2 proven base (counted-vmcnt depth-2, g2l16 both operands,
// XCD-bijective swizzle) + T2 bank-conflict swizzle:
//   The f16 [rows][32] tile (64B rows = 4x16B chunks) read at chunk=quad is
//   an 8-way bank conflict (even rows all on banks 0-3). Fix per rule 21
//   (g2l16 dest must stay linear): XOR the chunk index with (row>>1)&3 on
//   BOTH sides — global source chunk = (lane&3) ^ ((lane>>3)&3) at staging,
//   read chunk xq = quad ^ ((l16>>1)&3). Involution; all wave row-bases are
//   multiples of 16 so xq is per-thread constant. Result: 2-way (free).
template <int TBM, int TBN, typename OT, bool BIAS>
__global__ __launch_bounds__(256) void gemm_bt(
    const f16* __restrict__ A, const f16* __restrict__ Bt, OT* __restrict__ C,
    const float* __restrict__ bias, int M, int N, int K)
{
    constexpr int MI = TBM / 32;   // A-fragments per wave
    constexpr int NF = TBN / 32;   // B-fragments per wave
    constexpr int HM = TBM / 2;    // per-wave M span
    constexpr int HN = TBN / 2;    // per-wave N span
    constexpr int L  = TBM / 64 + TBN / 64;  // g2l16 per thread per tile
    __shared__ f16 As[2][TBM * BK];
    __shared__ f16 Bs[2][TBN * BK];

    const int tid  = threadIdx.x;
    const int lane = tid & 63;
    const int w    = tid >> 6;
    const int wm   = w & 1;
    const int wn   = w >> 1;
    const int l16  = lane & 15;
    const int quad = lane >> 4;
    const int xq   = quad ^ ((l16 >> 1) & 3);   // swizzled read chunk

    // XCD swizzle: HW round-robins consecutive dispatches across 8 XCDs.
    const int nbx = N / TBN;
    const int nb  = gridDim.x;
    int d = blockIdx.x;
    int wgid = ((nb & 7) == 0) ? ((d & 7) * (nb >> 3) + (d >> 3)) : d;
    int by = wgid / nbx;
    int bx = wgid - by * nbx;
    const int bm = by * TBM;
    const int bn = bx * TBN;

    // Staging: per 16B chunk, row = lane>>2, chunk = (lane&3) XOR'd with
    // (row>>1)&3 = (lane>>3)&3 so the LINEAR g2l16 write produces the
    // swizzled LDS image the xq read expects.
    const int srow = lane >> 2;
    const int scol = ((lane & 3) ^ ((lane >> 3) & 3)) * 8;
    const f16* gA = A  + (size_t)(bm + w * (TBM / 4) + srow) * K + scol;
    const f16* gB = Bt + (size_t)(bn + w * (TBN / 4) + srow) * K + scol;

    f32x4 acc[MI][NF] = {};

    auto STAGE = [&](int buf, int t) {
        const size_t k0 = (size_t)t * BK;
        f16* lA = &As[buf][(w * (TBM / 4)) * BK];
        f16* lB = &Bs[buf][(w * (TBN / 4)) * BK];
#pragma unroll
        for (int i = 0; i < (TBM / 4) / 16; ++i)
            g2l16(gA + k0 + i * 16 * (size_t)K, lA + i * 16 * BK);
#pragma unroll
        for (int i = 0; i < (TBN / 4) / 16; ++i)
            g2l16(gB + k0 + i * 16 * (size_t)K, lB + i * 16 * BK);
    };

    auto LOADFRAG = [&](int buf, f16x8* af, f16x8* bf) {
#pragma unroll
        for (int m = 0; m < MI; ++m)
            af[m] = *reinterpret_cast<const f16x8*>(
                &As[buf][(wm * HM + m * 16 + l16) * BK + xq * 8]);
#pragma unroll
        for (int n = 0; n < NF; ++n)
            bf[n] = *reinterpret_cast<const f16x8*>(
                &Bs[buf][(wn * HN + n * 16 + l16) * BK + xq * 8]);
    };

    auto MFMA_ALL = [&](f16x8* af, f16x8* bf) {
#pragma unroll
        for (int m = 0; m < MI; ++m)
#pragma unroll
            for (int n = 0; n < NF; ++n)
                acc[m][n] = __builtin_amdgcn_mfma_f32_16x16x32_f16(af[m], bf[n], acc[m][n], 0, 0, 0);
    };

    const int nk = K / BK;   // 64 for GEMM1, 16 for GEMM2 (even, >= 4)
    STAGE(0, 0);
    STAGE(1, 1);
    for (int t = 0; t < nk - 2; ++t) {
        wait_vmcnt<L>();                    // tile t landed; t+1 in flight
        __builtin_amdgcn_s_barrier();
        __builtin_amdgcn_sched_barrier(0);
        f16x8 af[MI], bf[NF];
        LOADFRAG(t & 1, af, bf);
        asm volatile("s_waitcnt lgkmcnt(0)" ::: "memory");
        __builtin_amdgcn_sched_barrier(0);  // my reads done before release
        __builtin_amdgcn_s_barrier();       // buf (t&1) released by all waves
        STAGE(t & 1, t + 2);                // async overwrite; overlaps MFMA
        MFMA_ALL(af, bf);
    }
    {   // t = nk-2: tiles nk-2, nk-1 in flight, nothing left to stage
        wait_vmcnt<L>();
        __builtin_amdgcn_s_barrier();
        __builtin_amdgcn_sched_barrier(0);
        f16x8 af[MI], bf[NF];
        LOADFRAG(nk & 1, af, bf);           // (nk-2)&1
        MFMA_ALL(af, bf);
    }
    {   // t = nk-1: drain fully
        wait_vmcnt<0>();
        __builtin_amdgcn_s_barrier();
        __builtin_amdgcn_sched_barrier(0);
        f16x8 af[MI], bf[NF];
        LOADFRAG((nk - 1) & 1, af, bf);
        MFMA_ALL(af, bf);
    }

    // epilogue: C/D layout row = quad*4 + r, col = lane&15
#pragma unroll
    for (int m = 0; m < MI; ++m) {
        int row_base = bm + wm * HM + m * 16 + quad * 4;
#pragma unroll
        for (int n = 0; n < NF; ++n) {
            int col = bn + wn * HN + n * 16 + l16;
            float b = BIAS ? bias[col] : 0.0f;
#pragma unroll
            for (int r = 0; r < 4; ++r) {
                float v = acc[m][n][r];
                size_t idx = (size_t)(row_base + r) * N + col;
                if constexpr (BIAS) C[idx] = (OT)(v + b);
                else                C[idx] = (OT)v;
            }
        }
    }
}

extern "C" void kernel_launch(void* const* d_in, const int* in_sizes, int n_in,
                              void* d_out, int out_size, void* d_ws, size_t ws_size,
                              hipStream_t stream)
{
    const float* x      = (const float*)d_in[0];
    const float* w_in   = (const float*)d_in[1];
    const float* w_out  = (const float*)d_in[2];
    const float* bias   = (const float*)d_in[3];
    const float* sc_in  = (const float*)d_in[4];
    const float* sc_out = (const float*)d_in[5];

    const int D = in_sizes[3];            // 2048
    const int R = in_sizes[1] / D;        // 512
    const int M = in_sizes[0] / D;        // 8192 (B*S)

    f16* winT  = (f16*)d_ws;                      // [R][D]
    f16* woutT = winT + (size_t)R * D;            // [D][R]
    f16* h     = woutT + (size_t)D * R;           // [M][R]
    f16* xh    = h + (size_t)M * R;               // [M][D]
    float* out = (float*)d_out;

    const int n8 = M * D / 8;
    const int nCastB  = (n8 + 255) / 256;
    const int nSpInB  = ((R / 4) * D + 255) / 256;
    const int nSpOutB = ((D / 4) * R + 255) / 256;
    prep_kernel<<<nCastB + nSpInB + nSpOutB, 256, 0, stream>>>(
        x, xh, n8, w_in, winT, sc_in, w_out, woutT, sc_out, D, R, nCastB, nSpInB);

    // GEMM1: M=8192, N=512, K=2048. 64x128 tile, 512 blocks = 2/CU.
    gemm_bt<64, 128, f16, false><<<(R / 128) * (M / 64), 256, 0, stream>>>(
        xh, winT, h, nullptr, M, R, D);
    // GEMM2: M=8192, N=2048, K=512. 128x128 tile, 1024 blocks = 4/CU.
    gemm_bt<128, 128, float, true><<<(D / 128) * (M / 128), 256, 0, stream>>>(
        h, woutT, out, bias, M, D, R);
}

// Round 7
// 174.402 us; speedup vs baseline: 1.1328x; 1.0309x over previous
//
#include <hip/hip_runtime.h>

typedef _Float16 f16;
typedef _Float16 f16x8 __attribute__((ext_vector_type(8)));
typedef float f32x4 __attribute__((ext_vector_type(4)));

// Async global->LDS, 16B per lane: lane i's 16B lands at base + i*16.
__device__ __forceinline__ void g2l16(const void* g, void* l) {
    __builtin_amdgcn_global_load_lds(
        (const __attribute__((address_space(1))) void*)g,
        (__attribute__((address_space(3))) void*)l, 16, 0, 0);
}

// Counted vmcnt wait (literal required in asm string).
template <int N> __device__ __forceinline__ void wait_vmcnt();
template <> __device__ __forceinline__ void wait_vmcnt<0>() { asm volatile("s_waitcnt vmcnt(0)" ::: "memory"); }
template <> __device__ __forceinline__ void wait_vmcnt<4>() { asm volatile("s_waitcnt vmcnt(4)" ::: "memory"); }
template <> __device__ __forceinline__ void wait_vmcnt<6>() { asm volatile("s_waitcnt vmcnt(6)" ::: "memory"); }

__device__ __forceinline__ float soft1(float a, float thr, float w, float s) {
    return copysignf(fmaxf(a - thr, 0.0f), w) * s;
}

__device__ __forceinline__ float thr4(float a0, float a1, float a2, float a3) {
    float lo01 = fminf(a0, a1), hi01 = fmaxf(a0, a1);
    float lo23 = fminf(a2, a3), hi23 = fmaxf(a2, a3);
    return fminf(fmaxf(lo01, lo23), fminf(hi01, hi23));
}

// One launch: [0, nCastB)        -> cast x fp32 -> f16 (cheaper than any
//             in-GEMM fusion: rounds 3/4 measured +32us for fused variants)
//             [nCastB, +nSpInB)  -> sparsify w_in   (2:4 along R), out winT  [R][D]
//             [.., +nSpOutB)     -> sparsify w_out^T (2:4 along D), out woutT [D][R]
__global__ __launch_bounds__(256) void prep_kernel(
    const float* __restrict__ x, f16* __restrict__ xh, int n8,
    const float* __restrict__ Wi, f16* __restrict__ winT, const float* __restrict__ sci,
    const float* __restrict__ Wo, f16* __restrict__ woutT, const float* __restrict__ sco,
    int D, int R, int nCastB, int nSpInB)
{
    int b = blockIdx.x;
    int tid = threadIdx.x;
    if (b < nCastB) {
        int i = b * 256 + tid;
        if (i < n8) {
            float4 a = reinterpret_cast<const float4*>(x)[2 * i];
            float4 c = reinterpret_cast<const float4*>(x)[2 * i + 1];
            f16x8 o = {(f16)a.x, (f16)a.y, (f16)a.z, (f16)a.w,
                       (f16)c.x, (f16)c.y, (f16)c.z, (f16)c.w};
            reinterpret_cast<f16x8*>(xh)[i] = o;
        }
    } else if (b < nCastB + nSpInB) {
        int t = (b - nCastB) * 256 + tid;   // t = rg*D + d (coalesced writes)
        int RG = R >> 2;
        if (t >= RG * D) return;
        int rg = t / D, d = t - rg * D;
        float s = *sci;
        float4 w = *reinterpret_cast<const float4*>(Wi + (size_t)d * R + rg * 4);
        float a0 = fabsf(w.x), a1 = fabsf(w.y), a2 = fabsf(w.z), a3 = fabsf(w.w);
        float thr = thr4(a0, a1, a2, a3);
        size_t base = (size_t)(rg * 4) * D + d;
        winT[base]                 = (f16)soft1(a0, thr, w.x, s);
        winT[base + D]             = (f16)soft1(a1, thr, w.y, s);
        winT[base + 2 * (size_t)D] = (f16)soft1(a2, thr, w.z, s);
        winT[base + 3 * (size_t)D] = (f16)soft1(a3, thr, w.w, s);
    } else {
        int t = (b - nCastB - nSpInB) * 256 + tid;  // t = dg*R + r
        if (t >= (D >> 2) * R) return;
        int dg = t / R, r = t - dg * R;
        float s = *sco;
        size_t i0 = (size_t)(dg * 4) * R + r;
        float w0 = Wo[i0], w1 = Wo[i0 + R], w2 = Wo[i0 + 2 * (size_t)R], w3 = Wo[i0 + 3 * (size_t)R];
        float a0 = fabsf(w0), a1 = fabsf(w1), a2 = fabsf(w2), a3 = fabsf(w3);
        float thr = thr4(a0, a1, a2, a3);
        woutT[i0]                 = (f16)soft1(a0, thr, w0, s);
        woutT[i0 + R]             = (f16)soft1(a1, thr, w1, s);
        woutT[i0 + 2 * (size_t)R] = (f16)soft1(a2, thr, w2, s);
        woutT[i0 + 3 * (size_t)R] = (f16)soft1(a3, thr, w3, s);
    }
}

// C[M][N] = A[M][K] f16 @ Bt[N][K]^T f16, fp32 accum.
// Counted-vmcnt depth-2 pipeline, g2l16 both operands, XCD-bijective
// swizzle, TBK-templated K-step:
//   TBK=64 (GEMM1): halves barrier-pairs (round-6 lesson: G1 is
//   sync/stall-bound at 8 MFMA per barrier-pair, not LDS-throughput-bound).
//   Per phase: 16 MFMA + 12 ds_read_b128 + 6 g2l16.
//   TBK=32 (GEMM2): 64KB dbuf at TBK=64 would halve occupancy (m132 trap).
// Bank swizzle (both-sides-or-neither, rule 21): rows are TBK*2 B, so
// chunk-of-16B c at row r maps to bank 4*((r*TBK/8 + c) mod 8 ...) — for
// both TBK the fix is c ^= r mod (TBK/8): source side via scol XOR at
// staging (LDS dest linear), read side via the same XOR on the chunk index.
template <int TBM, int TBN, int TBK, typename OT, bool BIAS>
__global__ __launch_bounds__(256) void gemm_bt(
    const f16* __restrict__ A, const f16* __restrict__ Bt, OT* __restrict__ C,
    const float* __restrict__ bias, int M, int N, int K)
{
    constexpr int KS = TBK / 32;   // 32-deep K-subtiles per LDS tile
    constexpr int MI = TBM / 32;   // A-fragments per wave per K-subtile
    constexpr int NF = TBN / 32;   // B-fragments per wave per K-subtile
    constexpr int HM = TBM / 2;    // per-wave M span
    constexpr int HN = TBN / 2;    // per-wave N span
    constexpr int RPO = 512 / TBK;            // rows covered per g2l16 wave-op
    constexpr int L  = (TBM + TBN) / 64 * KS; // g2l16 per thread per tile
    __shared__ f16 As[2][TBM * TBK];
    __shared__ f16 Bs[2][TBN * TBK];

    const int tid  = threadIdx.x;
    const int lane = tid & 63;
    const int w    = tid >> 6;
    const int wm   = w & 1;
    const int wn   = w >> 1;
    const int l16  = lane & 15;
    const int quad = lane >> 4;

    // XCD swizzle: HW round-robins consecutive dispatches across 8 XCDs.
    const int nbx = N / TBN;
    const int nb  = gridDim.x;
    int d = blockIdx.x;
    int wgid = ((nb & 7) == 0) ? ((d & 7) * (nb >> 3) + (d >> 3)) : d;
    int by = wgid / nbx;
    int bx = wgid - by * nbx;
    const int bm = by * TBM;
    const int bn = bx * TBN;

    // Staging: one wave-op = 64 lanes x 16B = RPO rows x TBK halves.
    //   TBK=32: row = lane>>2, chunk = (lane&3) ^ ((lane>>3)&3)
    //   TBK=64: row = lane>>3, chunk = (lane&7) ^ ((lane>>3)&7)
    constexpr int CPR = TBK / 8;              // 16B chunks per row
    const int srow = lane / CPR;
    const int scol = (((lane % CPR) ^ (srow % CPR)) ) * 8;
    const f16* gA = A  + (size_t)(bm + w * (TBM / 4) + srow) * K + scol;
    const f16* gB = Bt + (size_t)(bn + w * (TBN / 4) + srow) * K + scol;

    f32x4 acc[MI][NF] = {};

    auto STAGE = [&](int buf, int t) {
        const size_t k0 = (size_t)t * TBK;
        f16* lA = &As[buf][(w * (TBM / 4)) * TBK];
        f16* lB = &Bs[buf][(w * (TBN / 4)) * TBK];
#pragma unroll
        for (int i = 0; i < (TBM / 4) / RPO; ++i)
            g2l16(gA + k0 + i * RPO * (size_t)K, lA + i * RPO * TBK);
#pragma unroll
        for (int i = 0; i < (TBN / 4) / RPO; ++i)
            g2l16(gB + k0 + i * RPO * (size_t)K, lB + i * RPO * TBK);
    };

    // Fragment read: row's chunk index XOR'd with row % CPR (= l16 % CPR,
    // since all row bases are multiples of 16).
    auto LOADFRAG = [&](int buf, f16x8* af, f16x8* bf) {
#pragma unroll
        for (int ks = 0; ks < KS; ++ks) {
            const int xc = (l16 % CPR);
#pragma unroll
            for (int m = 0; m < MI; ++m) {
                int row = wm * HM + m * 16 + l16;
                int ch  = ((ks * 4 + quad) ^ xc) * 8;
                af[m * KS + ks] = *reinterpret_cast<const f16x8*>(&As[buf][row * TBK + ch]);
            }
#pragma unroll
            for (int n = 0; n < NF; ++n) {
                int row = wn * HN + n * 16 + l16;
                int ch  = ((ks * 4 + quad) ^ xc) * 8;
                bf[n * KS + ks] = *reinterpret_cast<const f16x8*>(&Bs[buf][row * TBK + ch]);
            }
        }
    };

    auto MFMA_ALL = [&](f16x8* af, f16x8* bf) {
#pragma unroll
        for (int ks = 0; ks < KS; ++ks)
#pragma unroll
            for (int m = 0; m < MI; ++m)
#pragma unroll
                for (int n = 0; n < NF; ++n)
                    acc[m][n] = __builtin_amdgcn_mfma_f32_16x16x32_f16(
                        af[m * KS + ks], bf[n * KS + ks], acc[m][n], 0, 0, 0);
    };

    const int nk = K / TBK;   // G1: 32 (TBK=64), G2: 16 (TBK=32)
    STAGE(0, 0);
    STAGE(1, 1);
    for (int t = 0; t < nk - 2; ++t) {
        wait_vmcnt<L>();                    // tile t landed; t+1 in flight
        __builtin_amdgcn_s_barrier();
        __builtin_amdgcn_sched_barrier(0);
        f16x8 af[MI * KS], bf[NF * KS];
        LOADFRAG(t & 1, af, bf);
        asm volatile("s_waitcnt lgkmcnt(0)" ::: "memory");
        __builtin_amdgcn_sched_barrier(0);  // my reads done before release
        __builtin_amdgcn_s_barrier();       // buf (t&1) released by all waves
        STAGE(t & 1, t + 2);                // async overwrite; overlaps MFMA
        MFMA_ALL(af, bf);
    }
    {   // t = nk-2: tiles nk-2, nk-1 in flight, nothing left to stage
        wait_vmcnt<L>();
        __builtin_amdgcn_s_barrier();
        __builtin_amdgcn_sched_barrier(0);
        f16x8 af[MI * KS], bf[NF * KS];
        LOADFRAG(nk & 1, af, bf);           // (nk-2)&1
        MFMA_ALL(af, bf);
    }
    {   // t = nk-1: drain fully
        wait_vmcnt<0>();
        __builtin_amdgcn_s_barrier();
        __builtin_amdgcn_sched_barrier(0);
        f16x8 af[MI * KS], bf[NF * KS];
        LOADFRAG((nk - 1) & 1, af, bf);
        MFMA_ALL(af, bf);
    }

    // epilogue: C/D layout row = quad*4 + r, col = lane&15
#pragma unroll
    for (int m = 0; m < MI; ++m) {
        int row_base = bm + wm * HM + m * 16 + quad * 4;
#pragma unroll
        for (int n = 0; n < NF; ++n) {
            int col = bn + wn * HN + n * 16 + l16;
            float b = BIAS ? bias[col] : 0.0f;
#pragma unroll
            for (int r = 0; r < 4; ++r) {
                float v = acc[m][n][r];
                size_t idx = (size_t)(row_base + r) * N + col;
                if constexpr (BIAS) C[idx] = (OT)(v + b);
                else                C[idx] = (OT)v;
            }
        }
    }
}

extern "C" void kernel_launch(void* const* d_in, const int* in_sizes, int n_in,
                              void* d_out, int out_size, void* d_ws, size_t ws_size,
                              hipStream_t stream)
{
    const float* x      = (const float*)d_in[0];
    const float* w_in   = (const float*)d_in[1];
    const float* w_out  = (const float*)d_in[2];
    const float* bias   = (const float*)d_in[3];
    const float* sc_in  = (const float*)d_in[4];
    const float* sc_out = (const float*)d_in[5];

    const int D = in_sizes[3];            // 2048
    const int R = in_sizes[1] / D;        // 512
    const int M = in_sizes[0] / D;        // 8192 (B*S)

    f16* winT  = (f16*)d_ws;                      // [R][D]
    f16* woutT = winT + (size_t)R * D;            // [D][R]
    f16* h     = woutT + (size_t)D * R;           // [M][R]
    f16* xh    = h + (size_t)M * R;               // [M][D]
    float* out = (float*)d_out;

    const int n8 = M * D / 8;
    const int nCastB  = (n8 + 255) / 256;
    const int nSpInB  = ((R / 4) * D + 255) / 256;
    const int nSpOutB = ((D / 4) * R + 255) / 256;
    prep_kernel<<<nCastB + nSpInB + nSpOutB, 256, 0, stream>>>(
        x, xh, n8, w_in, winT, sc_in, w_out, woutT, sc_out, D, R, nCastB, nSpInB);

    // GEMM1: M=8192, N=512, K=2048. 64x128 tile, TBK=64 (32 barrier-pairs,
    // 16 MFMA each), 48KB LDS dbuf, 512 blocks = 2/CU.
    gemm_bt<64, 128, 64, f16, false><<<(R / 128) * (M / 64), 256, 0, stream>>>(
        xh, winT, h, nullptr, M, R, D);
    // GEMM2: M=8192, N=2048, K=512. 128x128 tile, TBK=32 (keeps 4/CU),
    // 1024 blocks; near its 67MB fp32 output-write floor.
    gemm_bt<128, 128, 32, float, true><<<(D / 128) * (M / 128), 256, 0, stream>>>(
        h, woutT, out, bias, M, D, R);
}

// Round 8
// 173.965 us; speedup vs baseline: 1.1357x; 1.0025x over previous
//
#include <hip/hip_runtime.h>

typedef _Float16 f16;
typedef _Float16 f16x8 __attribute__((ext_vector_type(8)));
typedef float f32x4 __attribute__((ext_vector_type(4)));

// Async global->LDS, 16B per lane: lane i's 16B lands at base + i*16.
__device__ __forceinline__ void g2l16(const void* g, void* l) {
    __builtin_amdgcn_global_load_lds(
        (const __attribute__((address_space(1))) void*)g,
        (__attribute__((address_space(3))) void*)l, 16, 0, 0);
}

// Counted vmcnt wait (literal required in asm string).
template <int N> __device__ __forceinline__ void wait_vmcnt();
template <> __device__ __forceinline__ void wait_vmcnt<0>()  { asm volatile("s_waitcnt vmcnt(0)"  ::: "memory"); }
template <> __device__ __forceinline__ void wait_vmcnt<4>()  { asm volatile("s_waitcnt vmcnt(4)"  ::: "memory"); }
template <> __device__ __forceinline__ void wait_vmcnt<6>()  { asm volatile("s_waitcnt vmcnt(6)"  ::: "memory"); }
template <> __device__ __forceinline__ void wait_vmcnt<12>() { asm volatile("s_waitcnt vmcnt(12)" ::: "memory"); }

template <int V> struct ic { static constexpr int value = V; };

__device__ __forceinline__ float soft1(float a, float thr, float w, float s) {
    return copysignf(fmaxf(a - thr, 0.0f), w) * s;
}

__device__ __forceinline__ float thr4(float a0, float a1, float a2, float a3) {
    float lo01 = fminf(a0, a1), hi01 = fmaxf(a0, a1);
    float lo23 = fminf(a2, a3), hi23 = fmaxf(a2, a3);
    return fminf(fmaxf(lo01, lo23), fminf(hi01, hi23));
}

// One launch: [0, nCastB)        -> cast x fp32 -> f16 (cheaper than any
//             in-GEMM fusion: rounds 3/4 measured +32us for fused variants)
//             [nCastB, +nSpInB)  -> sparsify w_in   (2:4 along R), out winT  [R][D]
//             [.., +nSpOutB)     -> sparsify w_out^T (2:4 along D), out woutT [D][R]
__global__ __launch_bounds__(256) void prep_kernel(
    const float* __restrict__ x, f16* __restrict__ xh, int n8,
    const float* __restrict__ Wi, f16* __restrict__ winT, const float* __restrict__ sci,
    const float* __restrict__ Wo, f16* __restrict__ woutT, const float* __restrict__ sco,
    int D, int R, int nCastB, int nSpInB)
{
    int b = blockIdx.x;
    int tid = threadIdx.x;
    if (b < nCastB) {
        int i = b * 256 + tid;
        if (i < n8) {
            float4 a = reinterpret_cast<const float4*>(x)[2 * i];
            float4 c = reinterpret_cast<const float4*>(x)[2 * i + 1];
            f16x8 o = {(f16)a.x, (f16)a.y, (f16)a.z, (f16)a.w,
                       (f16)c.x, (f16)c.y, (f16)c.z, (f16)c.w};
            reinterpret_cast<f16x8*>(xh)[i] = o;
        }
    } else if (b < nCastB + nSpInB) {
        int t = (b - nCastB) * 256 + tid;   // t = rg*D + d (coalesced writes)
        int RG = R >> 2;
        if (t >= RG * D) return;
        int rg = t / D, d = t - rg * D;
        float s = *sci;
        float4 w = *reinterpret_cast<const float4*>(Wi + (size_t)d * R + rg * 4);
        float a0 = fabsf(w.x), a1 = fabsf(w.y), a2 = fabsf(w.z), a3 = fabsf(w.w);
        float thr = thr4(a0, a1, a2, a3);
        size_t base = (size_t)(rg * 4) * D + d;
        winT[base]                 = (f16)soft1(a0, thr, w.x, s);
        winT[base + D]             = (f16)soft1(a1, thr, w.y, s);
        winT[base + 2 * (size_t)D] = (f16)soft1(a2, thr, w.z, s);
        winT[base + 3 * (size_t)D] = (f16)soft1(a3, thr, w.w, s);
    } else {
        int t = (b - nCastB - nSpInB) * 256 + tid;  // t = dg*R + r
        if (t >= (D >> 2) * R) return;
        int dg = t / R, r = t - dg * R;
        float s = *sco;
        size_t i0 = (size_t)(dg * 4) * R + r;
        float w0 = Wo[i0], w1 = Wo[i0 + R], w2 = Wo[i0 + 2 * (size_t)R], w3 = Wo[i0 + 3 * (size_t)R];
        float a0 = fabsf(w0), a1 = fabsf(w1), a2 = fabsf(w2), a3 = fabsf(w3);
        float thr = thr4(a0, a1, a2, a3);
        woutT[i0]                 = (f16)soft1(a0, thr, w0, s);
        woutT[i0 + R]             = (f16)soft1(a1, thr, w1, s);
        woutT[i0 + 2 * (size_t)R] = (f16)soft1(a2, thr, w2, s);
        woutT[i0 + 3 * (size_t)R] = (f16)soft1(a3, thr, w3, s);
    }
}

// C[M][N] = A[M][K] f16 @ Bt[N][K]^T f16, fp32 accum.
// Counted-vmcnt DEPTH-buffered pipeline, g2l16 both operands,
// XCD-bijective block swizzle, TBK-templated K-step, chunk-XOR bank
// swizzle (both-sides, rule 21).
//   DEPTH=3 (GEMM1): round-7 back-solve showed ~400cy residual stall per
//   phase = load latency not covered by 1-tile-ahead prefetch at 2
//   blocks/CU. 2 tiles ahead (~700-800cy cover) should absorb it.
//   DEPTH=2 (GEMM2): K=512 -> 16 steps; pipeline too short for depth-3,
//   and 128^2/TBK=32 keeps 4 blocks/CU.
template <int TBM, int TBN, int TBK, int DEPTH, typename OT, bool BIAS>
__global__ __launch_bounds__(256) void gemm_bt(
    const f16* __restrict__ A, const f16* __restrict__ Bt, OT* __restrict__ C,
    const float* __restrict__ bias, int M, int N, int K)
{
    constexpr int KS = TBK / 32;   // 32-deep K-subtiles per LDS tile
    constexpr int MI = TBM / 32;   // A-fragments per wave per K-subtile
    constexpr int NF = TBN / 32;   // B-fragments per wave per K-subtile
    constexpr int HM = TBM / 2;    // per-wave M span
    constexpr int HN = TBN / 2;    // per-wave N span
    constexpr int RPO = 512 / TBK;            // rows covered per g2l16 wave-op
    constexpr int L  = (TBM + TBN) / 64 * KS; // g2l16 per thread per tile
    __shared__ f16 As[DEPTH][TBM * TBK];
    __shared__ f16 Bs[DEPTH][TBN * TBK];

    const int tid  = threadIdx.x;
    const int lane = tid & 63;
    const int w    = tid >> 6;
    const int wm   = w & 1;
    const int wn   = w >> 1;
    const int l16  = lane & 15;
    const int quad = lane >> 4;

    // XCD swizzle: HW round-robins consecutive dispatches across 8 XCDs.
    const int nbx = N / TBN;
    const int nb  = gridDim.x;
    int d = blockIdx.x;
    int wgid = ((nb & 7) == 0) ? ((d & 7) * (nb >> 3) + (d >> 3)) : d;
    int by = wgid / nbx;
    int bx = wgid - by * nbx;
    const int bm = by * TBM;
    const int bn = bx * TBN;

    // Staging: one wave-op = 64 lanes x 16B = RPO rows x TBK halves.
    // Chunk-XOR source swizzle (LDS dest linear, rule 21).
    constexpr int CPR = TBK / 8;              // 16B chunks per row
    const int srow = lane / CPR;
    const int scol = ((lane % CPR) ^ (srow % CPR)) * 8;
    const f16* gA = A  + (size_t)(bm + w * (TBM / 4) + srow) * K + scol;
    const f16* gB = Bt + (size_t)(bn + w * (TBN / 4) + srow) * K + scol;

    f32x4 acc[MI][NF] = {};

    auto STAGE = [&](int buf, int t) {
        const size_t k0 = (size_t)t * TBK;
        f16* lA = &As[buf][(w * (TBM / 4)) * TBK];
        f16* lB = &Bs[buf][(w * (TBN / 4)) * TBK];
#pragma unroll
        for (int i = 0; i < (TBM / 4) / RPO; ++i)
            g2l16(gA + k0 + i * RPO * (size_t)K, lA + i * RPO * TBK);
#pragma unroll
        for (int i = 0; i < (TBN / 4) / RPO; ++i)
            g2l16(gB + k0 + i * RPO * (size_t)K, lB + i * RPO * TBK);
    };

    // Fragment read: chunk index XOR'd with row % CPR (= l16 % CPR, since
    // all row bases are multiples of 16).
    auto LOADFRAG = [&](int buf, f16x8* af, f16x8* bf) {
        const int xc = (l16 % CPR);
#pragma unroll
        for (int ks = 0; ks < KS; ++ks) {
#pragma unroll
            for (int m = 0; m < MI; ++m) {
                int row = wm * HM + m * 16 + l16;
                int ch  = ((ks * 4 + quad) ^ xc) * 8;
                af[m * KS + ks] = *reinterpret_cast<const f16x8*>(&As[buf][row * TBK + ch]);
            }
#pragma unroll
            for (int n = 0; n < NF; ++n) {
                int row = wn * HN + n * 16 + l16;
                int ch  = ((ks * 4 + quad) ^ xc) * 8;
                bf[n * KS + ks] = *reinterpret_cast<const f16x8*>(&Bs[buf][row * TBK + ch]);
            }
        }
    };

    auto MFMA_ALL = [&](f16x8* af, f16x8* bf) {
#pragma unroll
        for (int ks = 0; ks < KS; ++ks)
#pragma unroll
            for (int m = 0; m < MI; ++m)
#pragma unroll
                for (int n = 0; n < NF; ++n)
                    acc[m][n] = __builtin_amdgcn_mfma_f32_16x16x32_f16(
                        af[m * KS + ks], bf[n * KS + ks], acc[m][n], 0, 0, 0);
    };

    const int nk = K / TBK;   // G1: 32 (TBK=64), G2: 16 (TBK=32)
#pragma unroll
    for (int p = 0; p < DEPTH; ++p)
        STAGE(p, p);
    int buf = 0;
    for (int t = 0; t < nk - DEPTH; ++t) {
        wait_vmcnt<(DEPTH - 1) * L>();      // tile t landed; t+1..t+DEPTH-1 in flight
        __builtin_amdgcn_s_barrier();
        __builtin_amdgcn_sched_barrier(0);
        f16x8 af[MI * KS], bf[NF * KS];
        LOADFRAG(buf, af, bf);
        asm volatile("s_waitcnt lgkmcnt(0)" ::: "memory");
        __builtin_amdgcn_sched_barrier(0);  // my reads done before release
        __builtin_amdgcn_s_barrier();       // buf released by all waves
        STAGE(buf, t + DEPTH);              // async overwrite; overlaps MFMA
        MFMA_ALL(af, bf);
        buf = (buf + 1 == DEPTH) ? 0 : buf + 1;
    }
    // tail: last DEPTH tiles, nothing left to stage; waits step down by L.
    auto TAILSTEP = [&](auto VM, int b) {
        wait_vmcnt<decltype(VM)::value>();
        __builtin_amdgcn_s_barrier();
        __builtin_amdgcn_sched_barrier(0);
        f16x8 af[MI * KS], bf[NF * KS];
        LOADFRAG(b, af, bf);
        MFMA_ALL(af, bf);
    };
    if constexpr (DEPTH == 3) {
        TAILSTEP(ic<2 * L>{}, buf);
        buf = (buf + 1 == DEPTH) ? 0 : buf + 1;
    }
    TAILSTEP(ic<L>{}, buf);
    buf = (buf + 1 == DEPTH) ? 0 : buf + 1;
    TAILSTEP(ic<0>{}, buf);

    // epilogue: C/D layout row = quad*4 + r, col = lane&15
#pragma unroll
    for (int m = 0; m < MI; ++m) {
        int row_base = bm + wm * HM + m * 16 + quad * 4;
#pragma unroll
        for (int n = 0; n < NF; ++n) {
            int col = bn + wn * HN + n * 16 + l16;
            float b = BIAS ? bias[col] : 0.0f;
#pragma unroll
            for (int r = 0; r < 4; ++r) {
                float v = acc[m][n][r];
                size_t idx = (size_t)(row_base + r) * N + col;
                if constexpr (BIAS) C[idx] = (OT)(v + b);
                else                C[idx] = (OT)v;
            }
        }
    }
}

extern "C" void kernel_launch(void* const* d_in, const int* in_sizes, int n_in,
                              void* d_out, int out_size, void* d_ws, size_t ws_size,
                              hipStream_t stream)
{
    const float* x      = (const float*)d_in[0];
    const float* w_in   = (const float*)d_in[1];
    const float* w_out  = (const float*)d_in[2];
    const float* bias   = (const float*)d_in[3];
    const float* sc_in  = (const float*)d_in[4];
    const float* sc_out = (const float*)d_in[5];

    const int D = in_sizes[3];            // 2048
    const int R = in_sizes[1] / D;        // 512
    const int M = in_sizes[0] / D;        // 8192 (B*S)

    f16* winT  = (f16*)d_ws;                      // [R][D]
    f16* woutT = winT + (size_t)R * D;            // [D][R]
    f16* h     = woutT + (size_t)D * R;           // [M][R]
    f16* xh    = h + (size_t)M * R;               // [M][D]
    float* out = (float*)d_out;

    const int n8 = M * D / 8;
    const int nCastB  = (n8 + 255) / 256;
    const int nSpInB  = ((R / 4) * D + 255) / 256;
    const int nSpOutB = ((D / 4) * R + 255) / 256;
    prep_kernel<<<nCastB + nSpInB + nSpOutB, 256, 0, stream>>>(
        x, xh, n8, w_in, winT, sc_in, w_out, woutT, sc_out, D, R, nCastB, nSpInB);

    // GEMM1: M=8192, N=512, K=2048. 64x128 tile, TBK=64, DEPTH=3 (2 tiles
    // in flight; 72KB LDS, still 2 blocks/CU), 512 blocks.
    gemm_bt<64, 128, 64, 3, f16, false><<<(R / 128) * (M / 64), 256, 0, stream>>>(
        xh, winT, h, nullptr, M, R, D);
    // GEMM2: M=8192, N=2048, K=512. 128x128 tile, TBK=32, DEPTH=2
    // (16 K-steps - too short for depth-3; keeps 4 blocks/CU), 1024 blocks.
    gemm_bt<128, 128, 32, 2, float, true><<<(D / 128) * (M / 128), 256, 0, stream>>>(
        h, woutT, out, bias, M, D, R);
}